// Round 12
// baseline (166.921 us; speedup 1.0000x reference)
//
#include <hip/hip_runtime.h>
#include <stdint.h>

// Problem constants
constexpr int CXR = 15, ECG = 14, EHR = 13;
constexpr int TOTAL = 42;
constexpr float LN_EPS = 1e-5f;

// Workspace layout (float offsets)
constexpr int WS_B    = 1848;                 // fused bias (42)
constexpr int WS_G    = WS_B + TOTAL;         // ln gamma (42)
constexpr int WS_BETA = WS_G + TOTAL;         // ln beta  (42)
constexpr int WS_FRAG = 1976;                 // W' fp16 A-frags (16B aligned)

// Tiling: 64 rows per wave, 2 waves per block, one-shot
constexpr int WROWS = 64;
constexpr int S0F = 0, S1F = WROWS * CXR, S2F = S1F + WROWS * ECG; // 0,960,1856
constexpr int ARENA_F = S2F + WROWS * EHR;    // 2688 floats: compact-out only
constexpr int WC0 = WROWS * CXR / 4, WC1 = WROWS * ECG / 4, WC2 = WROWS * EHR / 4;

typedef _Float16 half8 __attribute__((ext_vector_type(8)));
typedef float float4v __attribute__((ext_vector_type(4)));
typedef float f4a __attribute__((ext_vector_type(4), aligned(4)));  // dword-aligned vec load

struct FuseArgs {
    const float *in_w, *in_b, *out_w, *out_b, *kv_w, *kv_b, *ln_g, *ln_b;
    int E, R;
};

// Position -> global-feature map (must match the B-side loads in cmca_main):
//   t2=0 h=0: e -> feat e          (seg0 row start 0)
//   t2=0 h=1: e>=1 -> feat 7+e     (seg0 row start 7; e=0 dup -> W'=0)
//   t2=0 h=2: e -> feat 15+e       (seg1 row start 0)
//   t2=0 h=3: e>=2 -> feat 21+e    (seg1 row start 6; e<2 dup -> W'=0)
//   t2=1 h=0: e -> feat 29+e       (seg2 row start 0)
//   t2=1 h=1: e>=3 -> feat 34+e    (seg2 row start 5; e<3 dup -> W'=0)
//   t2=1 h>=2: all ZERO
__device__ __forceinline__ int pos_to_feat(int t, int h, int e) {
    if (t == 0) {
        if (h == 0) return e;
        if (h == 1) return (e >= 1) ? 7 + e : -1;
        if (h == 2) return 15 + e;
        return (e >= 2) ? 21 + e : -1;
    } else {
        if (h == 0) return 29 + e;
        if (h == 1) return (e >= 3) ? 34 + e : -1;
        return -1;
    }
}

// Single fuse kernel: block m computes A_eff rows of segment m (in shared),
// bias/gamma/beta to ws, then emits its own W' fp16 fragments.
__global__ void fuse_all_kernel(FuseArgs a0, FuseArgs a1, FuseArgs a2,
                                float* __restrict__ ws) {
    const int m = blockIdx.x;
    FuseArgs a = (m == 0) ? a0 : (m == 1 ? a1 : a2);
    const int E = a.E, R = a.R;
    const int tid = threadIdx.x;

    __shared__ float T1[15 * 42];
    __shared__ float b1[15];
    __shared__ float A[15 * 42];   // A_eff rows of this segment

    for (int idx = tid; idx < E * TOTAL; idx += blockDim.x) {
        int i = idx / TOTAL, j = idx % TOTAL;
        float acc = 0.f;
        for (int k = 0; k < E; ++k)
            acc = fmaf(a.in_w[(2 * E + i) * E + k], a.kv_w[k * TOTAL + j], acc);
        T1[i * TOTAL + j] = acc;
    }
    if (tid < E) {
        float acc = a.in_b[2 * E + tid];
        for (int k = 0; k < E; ++k)
            acc = fmaf(a.in_w[(2 * E + tid) * E + k], a.kv_b[k], acc);
        b1[tid] = acc;
    }
    __syncthreads();

    for (int idx = tid; idx < E * TOTAL; idx += blockDim.x) {
        int i = idx / TOTAL, j = idx % TOTAL;
        float acc = 0.f;
        for (int k = 0; k < E; ++k)
            acc = fmaf(a.out_w[i * E + k], T1[k * TOTAL + j], acc);
        A[i * TOTAL + j] = acc;
    }
    if (tid < E) {
        float acc = a.out_b[tid];
        for (int k = 0; k < E; ++k)
            acc = fmaf(a.out_w[tid * E + k], b1[k], acc);
        ws[WS_B + R + tid]    = acc;
        ws[WS_G + R + tid]    = a.ln_g[tid];
        ws[WS_BETA + R + tid] = a.ln_b[tid];
    }
    __syncthreads();

    // W' fragments: tid 0..127 -> t = tid>>6, lane l = tid&63.
    if (tid < 128) {
        const int l = tid & 63, t = tid >> 6;
        const int j = l & 15;          // feature row within m-tile
        const int h = l >> 4;
        half8 hv;
#pragma unroll
        for (int i = 0; i < 8; ++i) {
            int g = pos_to_feat(t, h, i);
            float v = 0.f;
            if (j < E && g >= 0) {
                v = A[j * TOTAL + g];
                if (g == R + j) v += 1.f;        // residual identity
            }
            hv[i] = (_Float16)v;
        }
        ((half8*)(ws + WS_FRAG))[(m * 2 + t) * 64 + l] = hv;
    }
}

__global__ __launch_bounds__(128, 4) void cmca_main(
        const float* __restrict__ cxr, const float* __restrict__ ecg,
        const float* __restrict__ ehr, const float* __restrict__ ws,
        float* __restrict__ out_cxr, float* __restrict__ out_ecg,
        float* __restrict__ out_ehr) {
    __shared__ __align__(16) float sbuf[2 * ARENA_F];
    const int tid = threadIdx.x;
    const int w = tid >> 6, lane = tid & 63;
    float* stg = sbuf + w * ARENA_F;              // compact-out buffer only
    const size_t gw = (size_t)blockIdx.x * 2 + w;
    const int h = lane >> 4, b15 = lane & 15;

    const float* g0 = cxr + gw * (size_t)(WROWS * CXR);
    const float* g1 = ecg + gw * (size_t)(WROWS * ECG);
    const float* g2 = ehr + gw * (size_t)(WROWS * EHR);

    // ---- W' fragments (L2-hot) ----
    const half8* fr = (const half8*)(ws + WS_FRAG);
    half8 wf[3][2];
#pragma unroll
    for (int m = 0; m < 3; ++m)
#pragma unroll
        for (int t = 0; t < 2; ++t) wf[m][t] = fr[(m * 2 + t) * 64 + lane];

    // ---- B-frags DIRECT from global; every load stays within its row ----
    // t2=0: h0 seg0 start 0 | h1 seg0 start 7 | h2 seg1 start 0 | h3 seg1 start 6
    // t2=1: h0 seg2 start 0 | h1 seg2 start 5 | h>=2 zeros (W'=0 there)
    const float* segA = (h < 2) ? g0 : g1;
    const int    lenA = (h < 2) ? 15 : 14;
    const int    offA = (h == 1) ? 7 : (h == 3 ? 6 : 0);

    float4v acc[3][4];
#pragma unroll
    for (int m = 0; m < 3; ++m)
#pragma unroll
        for (int n = 0; n < 4; ++n) acc[m][n] = float4v{0.f, 0.f, 0.f, 0.f};

#pragma unroll
    for (int n = 0; n < 4; ++n) {
        const int batch = n * 16 + b15;
        half8 x0, x1;

        const float* pA = segA + batch * lenA + offA;
        f4a ra0 = ((const f4a*)pA)[0];
        f4a ra1 = ((const f4a*)pA)[1];
#pragma unroll
        for (int e = 0; e < 4; ++e) {
            x0[e]     = (_Float16)ra0[e];
            x0[4 + e] = (_Float16)ra1[e];
        }

#pragma unroll
        for (int e = 0; e < 8; ++e) x1[e] = (_Float16)0.f;
        if (h < 2) {
            const float* pB = g2 + batch * 13 + ((h == 1) ? 5 : 0);
            f4a rb0 = ((const f4a*)pB)[0];
            f4a rb1 = ((const f4a*)pB)[1];
#pragma unroll
            for (int e = 0; e < 4; ++e) {
                x1[e]     = (_Float16)rb0[e];
                x1[4 + e] = (_Float16)rb1[e];
            }
        }

#pragma unroll
        for (int m = 0; m < 3; ++m) {
            acc[m][n] = __builtin_amdgcn_mfma_f32_16x16x32_f16(
                wf[m][0], x0, acc[m][n], 0, 0, 0);
            acc[m][n] = __builtin_amdgcn_mfma_f32_16x16x32_f16(
                wf[m][1], x1, acc[m][n], 0, 0, 0);
        }
    }

    // ---- epilogue: bias + in-register LN + compact LDS + coalesced store ----
    constexpr int Earr[3] = {CXR, ECG, EHR};
    constexpr int OFFa[3] = {0, CXR, CXR + ECG};
    constexpr int SEGF[3] = {S0F, S1F, S2F};
#pragma unroll
    for (int m = 0; m < 3; ++m) {
        const int E = Earr[m];
        const float invE = 1.0f / E;
        float bs[4], gm[4], bt[4];
#pragma unroll
        for (int r = 0; r < 4; ++r) {
            int j = 4 * h + r;
            bool v = j < E;
            bs[r] = v ? ws[WS_B + OFFa[m] + j] : 0.f;
            gm[r] = v ? ws[WS_G + OFFa[m] + j] : 0.f;
            bt[r] = v ? ws[WS_BETA + OFFa[m] + j] : 0.f;
        }
#pragma unroll
        for (int n = 0; n < 4; ++n) {
            float y0 = acc[m][n][0] + bs[0];
            float y1 = acc[m][n][1] + bs[1];
            float y2 = acc[m][n][2] + bs[2];
            float y3 = acc[m][n][3] + bs[3];
            float s  = (y0 + y1) + (y2 + y3);
            float ss = y0 * y0;
            ss = fmaf(y1, y1, ss);
            ss = fmaf(y2, y2, ss);
            ss = fmaf(y3, y3, ss);
            s  += __shfl_xor(s, 16, 64);
            ss += __shfl_xor(ss, 16, 64);
            s  += __shfl_xor(s, 32, 64);
            ss += __shfl_xor(ss, 32, 64);
            float mu  = s * invE;
            float var = fmaf(ss, invE, -mu * mu);
            float rs  = rsqrtf(var + LN_EPS);
            const int row = n * 16 + b15;
            float yv[4] = {y0, y1, y2, y3};
#pragma unroll
            for (int r = 0; r < 4; ++r) {
                int j = 4 * h + r;
                if (j < E)
                    stg[SEGF[m] + row * E + j] =
                        fmaf((yv[r] - mu) * rs, gm[r], bt[r]);
            }
        }
    }

    // ---- coalesced float4 stores from compact area (proven path) ----
    const float4v* w4 = (const float4v*)stg;
    float4v* o0 = (float4v*)(out_cxr + gw * (size_t)(WROWS * CXR));
    float4v* o1 = (float4v*)(out_ecg + gw * (size_t)(WROWS * ECG));
    float4v* o2 = (float4v*)(out_ehr + gw * (size_t)(WROWS * EHR));
#pragma unroll
    for (int it = 0; it < 4; ++it) {
        int idx = lane + it * 64;
        if (idx < WC0) o0[idx] = w4[idx];
    }
#pragma unroll
    for (int it = 0; it < 4; ++it) {
        int idx = lane + it * 64;
        if (idx < WC1) o1[idx] = w4[WC0 + idx];
    }
#pragma unroll
    for (int it = 0; it < 4; ++it) {
        int idx = lane + it * 64;
        if (idx < WC2) o2[idx] = w4[WC0 + WC1 + idx];
    }
}

extern "C" void kernel_launch(void* const* d_in, const int* in_sizes, int n_in,
                              void* d_out, int out_size, void* d_ws, size_t ws_size,
                              hipStream_t stream) {
    const float* cxr = (const float*)d_in[0];
    const float* ecg = (const float*)d_in[1];
    const float* ehr = (const float*)d_in[2];
    float* ws = (float*)d_ws;
    float* out = (float*)d_out;

    const size_t Bn = (size_t)in_sizes[0] / CXR;   // 2097152

    auto mk = [&](int base, int E, int R) {
        FuseArgs a;
        a.in_w  = (const float*)d_in[base + 0];
        a.in_b  = (const float*)d_in[base + 1];
        a.out_w = (const float*)d_in[base + 2];
        a.out_b = (const float*)d_in[base + 3];
        a.kv_w  = (const float*)d_in[base + 4];
        a.kv_b  = (const float*)d_in[base + 5];
        a.ln_g  = (const float*)d_in[base + 6];
        a.ln_b  = (const float*)d_in[base + 7];
        a.E = E; a.R = R;
        return a;
    };
    FuseArgs a0 = mk(3, CXR, 0);
    FuseArgs a1 = mk(11, ECG, CXR);
    FuseArgs a2 = mk(19, EHR, CXR + ECG);

    fuse_all_kernel<<<3, 256, 0, stream>>>(a0, a1, a2, ws);

    const int nblocks = (int)(Bn / (WROWS * 2));   // 16384 blocks x 2 waves
    cmca_main<<<nblocks, 128, 0, stream>>>(cxr, ecg, ehr, ws,
                                           out,
                                           out + Bn * CXR,
                                           out + Bn * (CXR + ECG));
}

// Round 14
// 152.759 us; speedup vs baseline: 1.0927x; 1.0927x over previous
//
#include <hip/hip_runtime.h>
#include <stdint.h>

// Problem constants
constexpr int CXR = 15, ECG = 14, EHR = 13;
constexpr int TOTAL = 42;
constexpr int MPITCH = 44;          // f32 fused-matrix row pitch (fuse1 output)
constexpr float LN_EPS = 1e-5f;

// Workspace layout (float offsets)
constexpr int WS_M    = 0;                    // A_eff f32, 42 x 44
constexpr int WS_B    = TOTAL * MPITCH;       // fused bias (42)
constexpr int WS_G    = WS_B + TOTAL;         // ln gamma (42)
constexpr int WS_BETA = WS_G + TOTAL;         // ln beta  (42)
constexpr int WS_FRAG = 1976;                 // W' fp16 A-frags (16B aligned)

// Tiling: 64 rows per wave, 2 waves per block, one-shot
constexpr int WROWS = 64;
constexpr int S0F = 0, S1F = WROWS * CXR, S2F = S1F + WROWS * ECG; // 0,960,1856
constexpr int WC0 = WROWS * CXR / 4, WC1 = WROWS * ECG / 4, WC2 = WROWS * EHR / 4;
constexpr int ARENA_B = 11264;     // per-wave arena: stage | fp16 tile | compact

typedef _Float16 half8 __attribute__((ext_vector_type(8)));
typedef __fp16 fp16x2 __attribute__((ext_vector_type(2)));   // cvt_pkrtz result type
typedef float float4v __attribute__((ext_vector_type(4)));

struct FuseArgs {
    const float *in_w, *in_b, *out_w, *out_b, *kv_w, *kv_b, *ln_g, *ln_b;
    int E, R;
};

// fuse1: A_eff = out_w @ Wv @ kv_w (E x 42), b_eff, ln params -> ws (f32)
__global__ void fuse_weights_kernel(FuseArgs a0, FuseArgs a1, FuseArgs a2,
                                    float* __restrict__ ws) {
    FuseArgs a = (blockIdx.x == 0) ? a0 : (blockIdx.x == 1 ? a1 : a2);
    const int E = a.E, R = a.R;
    const int tid = threadIdx.x;

    __shared__ float T1[15 * 42];
    __shared__ float b1[15];

    for (int idx = tid; idx < E * TOTAL; idx += blockDim.x) {
        int i = idx / TOTAL, j = idx % TOTAL;
        float acc = 0.f;
        for (int k = 0; k < E; ++k)
            acc = fmaf(a.in_w[(2 * E + i) * E + k], a.kv_w[k * TOTAL + j], acc);
        T1[i * TOTAL + j] = acc;
    }
    if (tid < E) {
        float acc = a.in_b[2 * E + tid];
        for (int k = 0; k < E; ++k)
            acc = fmaf(a.in_w[(2 * E + tid) * E + k], a.kv_b[k], acc);
        b1[tid] = acc;
    }
    __syncthreads();

    for (int idx = tid; idx < E * MPITCH; idx += blockDim.x) {
        int i = idx / MPITCH, j = idx % MPITCH;
        float acc = 0.f;
        if (j < TOTAL)
            for (int k = 0; k < E; ++k)
                acc = fmaf(a.out_w[i * E + k], T1[k * TOTAL + j], acc);
        ws[WS_M + (R + i) * MPITCH + j] = acc;
    }
    if (tid < E) {
        float acc = a.out_b[tid];
        for (int k = 0; k < E; ++k)
            acc = fmaf(a.out_w[tid * E + k], b1[k], acc);
        ws[WS_B + R + tid]    = acc;
        ws[WS_G + R + tid]    = a.ln_g[tid];
        ws[WS_BETA + R + tid] = a.ln_b[tid];
    }
}

// fuse2 (r8-proven): W' fp16 A-frags, MFMA lane order. Segment m padded to
// 16 feature rows (pad rows ZERO). k = t*32 + 8*(lane>>4) + i;
// k==feature adds identity (residual); k==42 is the bias column (x[42]=1).
__global__ void fuse_frags_kernel(float* __restrict__ ws) {
    const int tid = threadIdx.x;
    if (tid >= 384) return;
    const int l = tid & 63, nt = tid >> 6;   // nt = m*2 + t
    const int m = nt >> 1, t = nt & 1;
    const int j = l & 15;
    const int k0 = t * 32 + 8 * (l >> 4);
    const int offm = (m == 0) ? 0 : (m == 1 ? CXR : CXR + ECG);
    const int Em   = (m == 0) ? CXR : (m == 1 ? ECG : EHR);
    half8 h;
#pragma unroll
    for (int i = 0; i < 8; ++i) {
        int k = k0 + i;
        float v = 0.f;
        if (j < Em) {
            int glob = offm + j;
            if (k < TOTAL) {
                v = ws[WS_M + glob * MPITCH + k];
                if (k == glob) v += 1.f;          // residual identity
            } else if (k == TOTAL) {
                v = ws[WS_B + glob];              // bias via x[42]=1.0
            }
        }
        h[i] = (_Float16)v;
    }
    ((half8*)(ws + WS_FRAG))[nt * 64 + l] = h;
}

// Async global->LDS staging (linear, width 16).
template <int CH>
__device__ __forceinline__ void stage_seg(const float* __restrict__ g,
                                          float* lds_seg_base, int lane) {
#pragma unroll
    for (int it = 0; it < (CH + 63) / 64; ++it) {
        int idx = lane + it * 64;
        if (idx < CH) {
            const __attribute__((address_space(1))) void* src =
                (const __attribute__((address_space(1))) void*)
                    ((const char*)g + (size_t)idx * 16);
            __attribute__((address_space(3))) void* dst =
                (__attribute__((address_space(3))) void*)
                    ((char*)lds_seg_base + it * 1024);
            __builtin_amdgcn_global_load_lds(src, dst, 16, 0, 0);
        }
    }
}

__global__ __launch_bounds__(128) void cmca_main(
        const float* __restrict__ cxr, const float* __restrict__ ecg,
        const float* __restrict__ ehr, const float* __restrict__ ws,
        float* __restrict__ out_cxr, float* __restrict__ out_ecg,
        float* __restrict__ out_ehr) {
    __shared__ __align__(16) char smem[2 * ARENA_B];
    const int tid = threadIdx.x;
    const int w = tid >> 6, lane = tid & 63;
    char* arena = smem + w * ARENA_B;
    float* af = (float*)arena;          // stage / compact view
    const size_t gw = (size_t)blockIdx.x * 2 + w;
    const int h = lane >> 4, b15 = lane & 15;

    // ---- DMA stage this wave's 64-row tile (r7-proven) ----
    stage_seg<WC0>(cxr + gw * (size_t)(WROWS * CXR), af + S0F, lane);
    stage_seg<WC1>(ecg + gw * (size_t)(WROWS * ECG), af + S1F, lane);
    stage_seg<WC2>(ehr + gw * (size_t)(WROWS * EHR), af + S2F, lane);

    // ---- W' A-frags (overlap DMA; L2-hot) ----
    const half8* fr = (const half8*)(ws + WS_FRAG);
    half8 wf[3][2];
#pragma unroll
    for (int m = 0; m < 3; ++m)
#pragma unroll
        for (int t = 0; t < 2; ++t) wf[m][t] = fr[(m * 2 + t) * 64 + lane];

    asm volatile("s_waitcnt vmcnt(0)" ::: "memory");
    __builtin_amdgcn_sched_barrier(0);

    // ---- gather this lane's row (f32), 42 ds_read_b32 ----
    float x[TOTAL];
#pragma unroll
    for (int j = 0; j < CXR; ++j) x[j] = af[S0F + lane * CXR + j];
#pragma unroll
    for (int j = 0; j < ECG; ++j) x[CXR + j] = af[S1F + lane * ECG + j];
#pragma unroll
    for (int j = 0; j < EHR; ++j) x[CXR + ECG + j] = af[S2F + lane * EHR + j];
    asm volatile("s_waitcnt lgkmcnt(0)" ::: "memory");
    __builtin_amdgcn_sched_barrier(0);

    // ---- write fp16 X row (k 0..41 = x, 42 = 1.0, 43..63 = 0), swizzled ----
    // cvt_pkrtz packs 2 f32 -> 1 dword of 2 f16.
    const int swz = (lane & 7) << 4;
    {
#pragma unroll
        for (int j = 0; j < 5; ++j) {           // k = 0..39
            union { fp16x2 p[4]; half8 v; } u;
#pragma unroll
            for (int q = 0; q < 4; ++q)
                u.p[q] = __builtin_amdgcn_cvt_pkrtz(x[j * 8 + 2 * q],
                                                    x[j * 8 + 2 * q + 1]);
            *(half8*)(arena + ((lane * 128 + j * 16) ^ swz)) = u.v;
        }
        union { fp16x2 p[4]; half8 v; } u;      // k = 40..47
        u.p[0] = __builtin_amdgcn_cvt_pkrtz(x[40], x[41]);
        u.p[1] = __builtin_amdgcn_cvt_pkrtz(1.f, 0.f);
        u.p[2] = __builtin_amdgcn_cvt_pkrtz(0.f, 0.f);
        u.p[3] = u.p[2];
        *(half8*)(arena + ((lane * 128 + 80) ^ swz)) = u.v;
        float4v z = float4v{0.f, 0.f, 0.f, 0.f};
        *(float4v*)(arena + ((lane * 128 + 96) ^ swz))  = z;
        *(float4v*)(arena + ((lane * 128 + 112) ^ swz)) = z;
    }
    __builtin_amdgcn_sched_barrier(0);

    // ---- read B-frags (X^T): row = n*16 + b15, one b128 per (n,t2) ----
    half8 xf[4][2];
#pragma unroll
    for (int n = 0; n < 4; ++n) {
        int row = n * 16 + b15;
        int rsw = (row & 7) << 4;
#pragma unroll
        for (int t2 = 0; t2 < 2; ++t2)
            xf[n][t2] = *(const half8*)(arena +
                ((row * 128 + t2 * 64 + h * 16) ^ rsw));
    }
    asm volatile("s_waitcnt lgkmcnt(0)" ::: "memory");
    __builtin_amdgcn_sched_barrier(0);

    // ---- 24 MFMAs: Y^T[48 x 64] = W'[48 x 64k] * X^T[64k x 64] ----
    float4v acc[3][4];
#pragma unroll
    for (int m = 0; m < 3; ++m)
#pragma unroll
        for (int n = 0; n < 4; ++n) acc[m][n] = float4v{0.f, 0.f, 0.f, 0.f};
#pragma unroll
    for (int t2 = 0; t2 < 2; ++t2)
#pragma unroll
        for (int m = 0; m < 3; ++m)
#pragma unroll
            for (int n = 0; n < 4; ++n)
                acc[m][n] = __builtin_amdgcn_mfma_f32_16x16x32_f16(
                    wf[m][t2], xf[n][t2], acc[m][n], 0, 0, 0);
    __builtin_amdgcn_sched_barrier(0);

    // ---- in-register LN (r10-proven; pads contribute exact 0) ----
    constexpr int Earr[3] = {CXR, ECG, EHR};
    constexpr int OFFa[3] = {0, CXR, CXR + ECG};
    constexpr int SEGF[3] = {S0F, S1F, S2F};
#pragma unroll
    for (int m = 0; m < 3; ++m) {
        const int E = Earr[m];
        const float invE = 1.0f / E;
        float gm[4], bt[4];
#pragma unroll
        for (int r = 0; r < 4; ++r) {
            int j = 4 * h + r;
            bool v = j < E;
            gm[r] = v ? ws[WS_G + OFFa[m] + j] : 0.f;
            bt[r] = v ? ws[WS_BETA + OFFa[m] + j] : 0.f;
        }
#pragma unroll
        for (int n = 0; n < 4; ++n) {
            float y0 = acc[m][n][0], y1 = acc[m][n][1];
            float y2 = acc[m][n][2], y3 = acc[m][n][3];
            float s  = (y0 + y1) + (y2 + y3);
            float ss = y0 * y0;
            ss = fmaf(y1, y1, ss);
            ss = fmaf(y2, y2, ss);
            ss = fmaf(y3, y3, ss);
            s  += __shfl_xor(s, 16, 64);
            ss += __shfl_xor(ss, 16, 64);
            s  += __shfl_xor(s, 32, 64);
            ss += __shfl_xor(ss, 32, 64);
            float mu  = s * invE;
            float var = fmaf(ss, invE, -mu * mu);
            float rs  = rsqrtf(var + LN_EPS);
            const int row = n * 16 + b15;
            float yv[4] = {y0, y1, y2, y3};
#pragma unroll
            for (int r = 0; r < 4; ++r) {
                int j = 4 * h + r;
                if (j < E)
                    af[SEGF[m] + row * E + j] =
                        fmaf((yv[r] - mu) * rs, gm[r], bt[r]);
            }
        }
    }
    __builtin_amdgcn_sched_barrier(0);

    // ---- coalesced float4 stores from compact area (proven path) ----
    const float4v* w4 = (const float4v*)af;
    float4v* o0 = (float4v*)(out_cxr + gw * (size_t)(WROWS * CXR));
    float4v* o1 = (float4v*)(out_ecg + gw * (size_t)(WROWS * ECG));
    float4v* o2 = (float4v*)(out_ehr + gw * (size_t)(WROWS * EHR));
#pragma unroll
    for (int it = 0; it < 4; ++it) {
        int idx = lane + it * 64;
        if (idx < WC0) o0[idx] = w4[idx];
    }
#pragma unroll
    for (int it = 0; it < 4; ++it) {
        int idx = lane + it * 64;
        if (idx < WC1) o1[idx] = w4[WC0 + idx];
    }
#pragma unroll
    for (int it = 0; it < 4; ++it) {
        int idx = lane + it * 64;
        if (idx < WC2) o2[idx] = w4[WC0 + WC1 + idx];
    }
}

extern "C" void kernel_launch(void* const* d_in, const int* in_sizes, int n_in,
                              void* d_out, int out_size, void* d_ws, size_t ws_size,
                              hipStream_t stream) {
    const float* cxr = (const float*)d_in[0];
    const float* ecg = (const float*)d_in[1];
    const float* ehr = (const float*)d_in[2];
    float* ws = (float*)d_ws;
    float* out = (float*)d_out;

    const size_t Bn = (size_t)in_sizes[0] / CXR;   // 2097152

    auto mk = [&](int base, int E, int R) {
        FuseArgs a;
        a.in_w  = (const float*)d_in[base + 0];
        a.in_b  = (const float*)d_in[base + 1];
        a.out_w = (const float*)d_in[base + 2];
        a.out_b = (const float*)d_in[base + 3];
        a.kv_w  = (const float*)d_in[base + 4];
        a.kv_b  = (const float*)d_in[base + 5];
        a.ln_g  = (const float*)d_in[base + 6];
        a.ln_b  = (const float*)d_in[base + 7];
        a.E = E; a.R = R;
        return a;
    };
    FuseArgs a0 = mk(3, CXR, 0);
    FuseArgs a1 = mk(11, ECG, CXR);
    FuseArgs a2 = mk(19, EHR, CXR + ECG);

    fuse_weights_kernel<<<3, 256, 0, stream>>>(a0, a1, a2, ws);
    fuse_frags_kernel<<<1, 384, 0, stream>>>(ws);

    const int nblocks = (int)(Bn / (WROWS * 2));   // 16384 blocks x 2 waves
    cmca_main<<<nblocks, 128, 0, stream>>>(cxr, ecg, ehr, ws,
                                           out,
                                           out + Bn * CXR,
                                           out + Bn * (CXR + ECG));
}

// Round 15
// 145.374 us; speedup vs baseline: 1.1482x; 1.0508x over previous
//
#include <hip/hip_runtime.h>
#include <stdint.h>

// Problem constants
constexpr int CXR = 15, ECG = 14, EHR = 13;
constexpr int TOTAL = 42;
constexpr int MPITCH = 44;
constexpr float LN_EPS = 1e-5f;

// Workspace layout (float offsets)
constexpr int WS_B    = 1848;                 // fused bias (42)
constexpr int WS_G    = WS_B + TOTAL;         // ln gamma (42)
constexpr int WS_BETA = WS_G + TOTAL;         // ln beta  (42)
constexpr int WS_FRAG = 1976;                 // fp16 B-fragments (16B aligned)

// Tiling: 64 rows per wave, 2 waves per block, one-shot (r7-proven)
constexpr int WROWS = 64;
constexpr int ARENA_B = 11264;                // per-wave LDS arena (bytes)
constexpr int S0F = 0, S1F = WROWS * CXR, S2F = S1F + WROWS * ECG;  // 0,960,1856
constexpr int WC0 = WROWS * CXR / 4, WC1 = WROWS * ECG / 4, WC2 = WROWS * EHR / 4;

typedef _Float16 half8 __attribute__((ext_vector_type(8)));
typedef float float4v __attribute__((ext_vector_type(4)));

struct FuseArgs {
    const float *in_w, *in_b, *out_w, *out_b, *kv_w, *kv_b, *ln_g, *ln_b;
    int E, R;
};

// Merged fuse kernel (r11-proven structure): block m computes its segment's
// A_eff in shared, writes bias/gamma/beta, then emits W' fp16 B-fragments
// with r7's verified k-packing: W[k][col] = A_eff[col][k] (+ identity at
// k==col, bias row at k==42). Frag elem i <-> k = t*32 + 8*(lane>>4) + i.
__global__ void fuse_all_kernel(FuseArgs a0, FuseArgs a1, FuseArgs a2,
                                float* __restrict__ ws) {
    const int m = blockIdx.x;
    FuseArgs a = (m == 0) ? a0 : (m == 1 ? a1 : a2);
    const int E = a.E, R = a.R;
    const int tid = threadIdx.x;

    __shared__ float T1[15 * 42];
    __shared__ float b1[15];
    __shared__ float A[15 * 42];      // A_eff rows of this segment
    __shared__ float beff[15];        // fused bias of this segment

    for (int idx = tid; idx < E * TOTAL; idx += blockDim.x) {
        int i = idx / TOTAL, j = idx % TOTAL;
        float acc = 0.f;
        for (int k = 0; k < E; ++k)
            acc = fmaf(a.in_w[(2 * E + i) * E + k], a.kv_w[k * TOTAL + j], acc);
        T1[i * TOTAL + j] = acc;
    }
    if (tid < E) {
        float acc = a.in_b[2 * E + tid];
        for (int k = 0; k < E; ++k)
            acc = fmaf(a.in_w[(2 * E + tid) * E + k], a.kv_b[k], acc);
        b1[tid] = acc;
    }
    __syncthreads();

    for (int idx = tid; idx < E * TOTAL; idx += blockDim.x) {
        int i = idx / TOTAL, j = idx % TOTAL;
        float acc = 0.f;
        for (int k = 0; k < E; ++k)
            acc = fmaf(a.out_w[i * E + k], T1[k * TOTAL + j], acc);
        A[i * TOTAL + j] = acc;
    }
    if (tid < E) {
        float acc = a.out_b[tid];
        for (int k = 0; k < E; ++k)
            acc = fmaf(a.out_w[tid * E + k], b1[k], acc);
        beff[tid]             = acc;
        ws[WS_B + R + tid]    = acc;
        ws[WS_G + R + tid]    = a.ln_g[tid];
        ws[WS_BETA + R + tid] = a.ln_b[tid];
    }
    __syncthreads();

    // B-fragments for output columns [R, R+E) within the 48-wide n-tiles.
    // Frag (n, t): lane&15 = global col c = n*16 + (l&15); elem i <-> k.
    // This block only fills cols of ITS segment; cols outside are written
    // by the owning block (every col 0..41 is covered exactly once; cols
    // 42..47 default 0 — block 2 zero-fills them).
    if (tid < 128) {
        const int l = tid & 63, t = tid >> 6;
        const int k0 = t * 32 + 8 * (l >> 4);
        // which n-tiles contain this segment's columns?
#pragma unroll
        for (int n = 0; n < 3; ++n) {
            const int c = n * 16 + (l & 15);
            const int j = c - R;                 // local feature
            const bool mine = (j >= 0 && j < E);
            const bool pad  = (c >= TOTAL) && (m == 2);   // cols 42..47
            if (!mine && !pad) continue;
            half8 h;
#pragma unroll
            for (int i = 0; i < 8; ++i) {
                int k = k0 + i;
                float v = 0.f;
                if (mine) {
                    if (k < TOTAL) {
                        v = A[j * TOTAL + k];
                        if (k == c) v += 1.f;     // residual identity
                    } else if (k == TOTAL) {
                        v = beff[j];              // bias via x[42]=1.0
                    }
                }
                h[i] = (_Float16)v;
            }
            ((half8*)(ws + WS_FRAG))[(n * 2 + t) * 64 + l] = h;
        }
    }
}

// Async global->LDS staging (linear, width 16) — r7-proven.
template <int CH>
__device__ __forceinline__ void stage_wave(const float* __restrict__ g,
                                           float* lds_seg_base, int lane) {
#pragma unroll
    for (int it = 0; it < (CH + 63) / 64; ++it) {
        int idx = lane + it * 64;
        if (idx < CH) {
            const __attribute__((address_space(1))) void* src =
                (const __attribute__((address_space(1))) void*)
                    ((const char*)g + (size_t)idx * 16);
            __attribute__((address_space(3))) void* dst =
                (__attribute__((address_space(3))) void*)
                    ((char*)lds_seg_base + it * 1024);
            __builtin_amdgcn_global_load_lds(src, dst, 16, 0, 0);
        }
    }
}

// cmca_main: byte-for-byte round 7 (146.5 µs champion).
__global__ __launch_bounds__(128) void cmca_main(
        const float* __restrict__ cxr, const float* __restrict__ ecg,
        const float* __restrict__ ehr, const float* __restrict__ ws,
        float* __restrict__ out_cxr, float* __restrict__ out_ecg,
        float* __restrict__ out_ehr) {
    __shared__ __align__(16) char smem[2 * ARENA_B];
    const int tid = threadIdx.x;
    const int w = tid >> 6, lane = tid & 63;
    char* arena = smem + w * ARENA_B;
    float* af = (float*)arena;
    const size_t gw = (size_t)blockIdx.x * 2 + w;

    // ---- B-fragments (6 x 16B coalesced, L2-hot) ----
    const half8* fr = (const half8*)(ws + WS_FRAG);
    half8 bfrag[6];
#pragma unroll
    for (int q = 0; q < 6; ++q) bfrag[q] = fr[q * 64 + lane];

    // ---- stage all three segments into arena (linear f32) ----
    stage_wave<WC0>(cxr + gw * (size_t)(WROWS * CXR), af + S0F, lane);
    stage_wave<WC1>(ecg + gw * (size_t)(WROWS * ECG), af + S1F, lane);
    stage_wave<WC2>(ehr + gw * (size_t)(WROWS * EHR), af + S2F, lane);
    asm volatile("s_waitcnt vmcnt(0)" ::: "memory");

    // ---- gather this lane's row (f32) ----
    float x[TOTAL];
#pragma unroll
    for (int j = 0; j < CXR; ++j) x[j] = af[S0F + lane * CXR + j];
#pragma unroll
    for (int j = 0; j < ECG; ++j) x[CXR + j] = af[S1F + lane * ECG + j];
#pragma unroll
    for (int j = 0; j < EHR; ++j) x[CXR + ECG + j] = af[S2F + lane * EHR + j];
    __builtin_amdgcn_sched_barrier(0);

    // ---- write fp16 X row [64 halfs], swizzled; x[42]=1.0, pad=0 ----
    {
        const int swz = (lane & 7) << 4;
#pragma unroll
        for (int j = 0; j < 8; ++j) {
            half8 h;
#pragma unroll
            for (int e = 0; e < 8; ++e) {
                int idx = j * 8 + e;
                float v = (idx < TOTAL) ? x[idx] : (idx == TOTAL ? 1.f : 0.f);
                h[e] = (_Float16)v;
            }
            *(half8*)(arena + ((lane * 128 + j * 16) ^ swz)) = h;
        }
    }
    __builtin_amdgcn_sched_barrier(0);

    // ---- read A-fragments (one b128 per m,t) ----
    half8 afr[4][2];
#pragma unroll
    for (int m = 0; m < 4; ++m) {
        int row = m * 16 + (lane & 15);
        int rswz = (row & 7) << 4;
#pragma unroll
        for (int t = 0; t < 2; ++t)
            afr[m][t] = *(const half8*)(arena +
                ((row * 128 + t * 64 + (lane >> 4) * 16) ^ rswz));
    }
    __builtin_amdgcn_sched_barrier(0);

    // ---- 24 MFMAs: Y[64x48] = X[64x64] * W[64x48] ----
    float4v acc[4][3];
#pragma unroll
    for (int m = 0; m < 4; ++m)
#pragma unroll
        for (int n = 0; n < 3; ++n) acc[m][n] = float4v{0.f, 0.f, 0.f, 0.f};
#pragma unroll
    for (int t = 0; t < 2; ++t)
#pragma unroll
        for (int m = 0; m < 4; ++m)
#pragma unroll
            for (int n = 0; n < 3; ++n)
                acc[m][n] = __builtin_amdgcn_mfma_f32_16x16x32_f16(
                    afr[m][t], bfrag[n * 2 + t], acc[m][n], 0, 0, 0);

    // ---- scatter y to [row][44] f32 tile ----
    __builtin_amdgcn_sched_barrier(0);
#pragma unroll
    for (int m = 0; m < 4; ++m)
#pragma unroll
        for (int n = 0; n < 3; ++n)
#pragma unroll
            for (int r = 0; r < 4; ++r) {
                int row = m * 16 + (lane >> 4) * 4 + r;
                int col = n * 16 + (lane & 15);
                if (col < MPITCH) af[row * MPITCH + col] = acc[m][n][r];
            }
    __builtin_amdgcn_sched_barrier(0);

    // ---- epilogue (lane = row): gather y, per-segment LN, compact write ----
    float y[MPITCH];
#pragma unroll
    for (int j = 0; j < 11; ++j) {
        float4v q = *(const float4v*)(af + lane * MPITCH + j * 4);
        y[j * 4 + 0] = q[0]; y[j * 4 + 1] = q[1];
        y[j * 4 + 2] = q[2]; y[j * 4 + 3] = q[3];
    }
    __builtin_amdgcn_sched_barrier(0);

    float res[TOTAL];
    {
#define LN_SEG(S, E)                                                       \
        {                                                                  \
            float mu = 0.f;                                                \
            _Pragma("unroll")                                              \
            for (int i = 0; i < (E); ++i) mu += y[(S) + i];                \
            mu *= (1.0f / (E));                                            \
            float var = 0.f;                                               \
            _Pragma("unroll")                                              \
            for (int i = 0; i < (E); ++i) {                                \
                float d = y[(S) + i] - mu; var = fmaf(d, d, var);          \
            }                                                              \
            var *= (1.0f / (E));                                           \
            float rs = rsqrtf(var + LN_EPS);                               \
            _Pragma("unroll")                                              \
            for (int i = 0; i < (E); ++i) {                                \
                float nv = (y[(S) + i] - mu) * rs;                         \
                res[(S) + i] = fmaf(nv, ws[WS_G + (S) + i],                \
                                    ws[WS_BETA + (S) + i]);                \
            }                                                              \
        }
        LN_SEG(0, CXR)
        LN_SEG(CXR, ECG)
        LN_SEG(CXR + ECG, EHR)
#undef LN_SEG
    }
#pragma unroll
    for (int j = 0; j < CXR; ++j) af[S0F + lane * CXR + j] = res[j];
#pragma unroll
    for (int j = 0; j < ECG; ++j) af[S1F + lane * ECG + j] = res[CXR + j];
#pragma unroll
    for (int j = 0; j < EHR; ++j) af[S2F + lane * EHR + j] = res[CXR + ECG + j];
    __builtin_amdgcn_sched_barrier(0);

    // ---- coalesced float4 stores ----
    const float4v* wb4 = (const float4v*)af;
    float4v* o0 = (float4v*)(out_cxr + gw * (size_t)(WROWS * CXR));
    float4v* o1 = (float4v*)(out_ecg + gw * (size_t)(WROWS * ECG));
    float4v* o2 = (float4v*)(out_ehr + gw * (size_t)(WROWS * EHR));
#pragma unroll
    for (int it = 0; it < 4; ++it) {
        int idx = lane + it * 64;
        if (idx < WC0) o0[idx] = wb4[idx];
    }
#pragma unroll
    for (int it = 0; it < 4; ++it) {
        int idx = lane + it * 64;
        if (idx < WC1) o1[idx] = wb4[WC0 + idx];
    }
#pragma unroll
    for (int it = 0; it < 4; ++it) {
        int idx = lane + it * 64;
        if (idx < WC2) o2[idx] = wb4[WC0 + WC1 + idx];
    }
}

extern "C" void kernel_launch(void* const* d_in, const int* in_sizes, int n_in,
                              void* d_out, int out_size, void* d_ws, size_t ws_size,
                              hipStream_t stream) {
    const float* cxr = (const float*)d_in[0];
    const float* ecg = (const float*)d_in[1];
    const float* ehr = (const float*)d_in[2];
    float* ws = (float*)d_ws;
    float* out = (float*)d_out;

    const size_t Bn = (size_t)in_sizes[0] / CXR;   // 2097152

    auto mk = [&](int base, int E, int R) {
        FuseArgs a;
        a.in_w  = (const float*)d_in[base + 0];
        a.in_b  = (const float*)d_in[base + 1];
        a.out_w = (const float*)d_in[base + 2];
        a.out_b = (const float*)d_in[base + 3];
        a.kv_w  = (const float*)d_in[base + 4];
        a.kv_b  = (const float*)d_in[base + 5];
        a.ln_g  = (const float*)d_in[base + 6];
        a.ln_b  = (const float*)d_in[base + 7];
        a.E = E; a.R = R;
        return a;
    };
    FuseArgs a0 = mk(3, CXR, 0);
    FuseArgs a1 = mk(11, ECG, CXR);
    FuseArgs a2 = mk(19, EHR, CXR + ECG);

    fuse_all_kernel<<<3, 256, 0, stream>>>(a0, a1, a2, ws);

    const int nblocks = (int)(Bn / (WROWS * 2));   // 16384 blocks x 2 waves
    cmca_main<<<nblocks, 128, 0, stream>>>(cxr, ecg, ehr, ws,
                                           out,
                                           out + Bn * CXR,
                                           out + Bn * (CXR + ECG));
}